// Round 2
// baseline (377.548 us; speedup 1.0000x reference)
//
#include <hip/hip_runtime.h>
#include <stdint.h>

#define Bb 8
#define Nn 16384
#define Cc 40
#define Ee 512
#define Dd 256

typedef __attribute__((ext_vector_type(4))) float f32x4;
typedef __attribute__((ext_vector_type(8))) short bf16x8;

__device__ __forceinline__ unsigned short f2bf(float f) {
  union { float f; uint32_t u; } x; x.f = f;
  uint32_t r = x.u + 0x7FFFu + ((x.u >> 16) & 1u);   // round-to-nearest-even
  return (unsigned short)(r >> 16);
}
__device__ __forceinline__ unsigned int pack2(float a, float b) {
  return (unsigned int)f2bf(a) | ((unsigned int)f2bf(b) << 16);
}

// ---------------- prep0: Mt[d][e] = sum_f Wq[f][e]*Wk[f][d];
//                  tvec[e] = Wq^T bk; uvec[d] = Wk^T bq; bqbk = bq.bk -------------
// grid (8,16), 256 thr: thread -> e = bx*64+(t&63), d = by*16 + (t>>6)*4
__global__ __launch_bounds__(256) void prep0_kernel(
    const float* __restrict__ Wq, const float* __restrict__ Wk,
    const float* __restrict__ bq, const float* __restrict__ bk,
    float* __restrict__ Mt, float* __restrict__ tvec,
    float* __restrict__ uvec, float* __restrict__ bqbk) {
  const int t = threadIdx.x;
  const int el = t & 63, dq = t >> 6;
  const int e = blockIdx.x * 64 + el;
  const int d = blockIdx.y * 16 + dq * 4;
  float4 m = {0,0,0,0};
  float te = 0.f;
  float4 ua = {0,0,0,0};
  float bb = 0.f;
  const bool do_t = (blockIdx.y == 0) && (dq == 0);
  const bool do_u = (blockIdx.x == 0);
  #pragma unroll 4
  for (int f = 0; f < Ee; f++) {
    float wq = Wq[(size_t)f * Ee + e];
    float4 wk4 = *(const float4*)(Wk + (size_t)f * Dd + d);
    float bkf = bk[f], bqf = bq[f];
    m.x += wq * wk4.x; m.y += wq * wk4.y; m.z += wq * wk4.z; m.w += wq * wk4.w;
    if (do_t) te += wq * bkf;
    if (do_u) {
      ua.x += wk4.x * bqf; ua.y += wk4.y * bqf;
      ua.z += wk4.z * bqf; ua.w += wk4.w * bqf;
      bb += bqf * bkf;
    }
  }
  Mt[(size_t)(d+0)*Ee + e] = m.x;
  Mt[(size_t)(d+1)*Ee + e] = m.y;
  Mt[(size_t)(d+2)*Ee + e] = m.z;
  Mt[(size_t)(d+3)*Ee + e] = m.w;
  if (do_t) tvec[e] = te;
  if (do_u && el == 0) {
    uvec[d+0] = ua.x; uvec[d+1] = ua.y; uvec[d+2] = ua.z; uvec[d+3] = ua.w;
  }
  if (blockIdx.x == 0 && blockIdx.y == 0 && t == 0) bqbk[0] = bb;
}

// ---------------- prep1: G[e][bc] = scale*(Mt.k_bc + t[e]) -> A-frags (pads=0);
//                  dbias[b*64+c] = scale*(u.k_bc + bqbk) ----------------
// grid (48,4): bx -> 8 slots of (b, c in 0..47); by -> e-group of 128
__global__ __launch_bounds__(256) void prep1_kernel(
    const float* __restrict__ k, const float* __restrict__ Mt,
    const float* __restrict__ tvec, const float* __restrict__ uvec,
    const float* __restrict__ bqbk, unsigned short* __restrict__ abf,
    float* __restrict__ dbias) {
  __shared__ float kL[8][Dd];
  const int t = threadIdx.x;
  const int el = t & 127, half = t >> 7;
  const int e = blockIdx.y * 128 + el;
  const int sbase = blockIdx.x * 8;
  for (int i = t; i < 8 * Dd; i += 256) {
    int row = i >> 8, dd = i & (Dd - 1);
    int sg = sbase + row, bb_ = sg / 48, cc = sg % 48;
    kL[row][dd] = (cc < 40) ? k[((size_t)bb_ * Cc + cc) * Dd + dd] : 0.f;
  }
  __syncthreads();
  float acc[4] = {0,0,0,0};
  float db[4]  = {0,0,0,0};
  #pragma unroll 4
  for (int d = 0; d < Dd; d++) {
    float mt = Mt[(size_t)d * Ee + e];
    float ud = uvec[d];
    #pragma unroll
    for (int si = 0; si < 4; si++) {
      float kv = kL[half*4 + si][d];
      acc[si] += mt * kv;
      db[si]  += ud * kv;
    }
  }
  const float scale = 0.044194173824159216f;  // 1/sqrt(512)
  const float te = tvec[e];
  const float bqbkv = bqbk[0];
  const int ks = e >> 5, gg = (e >> 3) & 3, j = e & 7;
  #pragma unroll
  for (int si = 0; si < 4; si++) {
    int sg = sbase + half*4 + si, bb_ = sg / 48, cc = sg % 48;
    int ct = cc >> 4, lane16 = (cc & 15) + 16*gg;
    unsigned short val = (cc < 40) ? f2bf(scale * (acc[si] + te)) : (unsigned short)0;
    abf[((((size_t)bb_*3 + ct)*16 + ks)*64 + lane16)*8 + j] = val;
    if (el == 0) dbias[bb_*64 + cc] = (cc < 40) ? scale * (db[si] + bqbkv) : 0.f;
  }
}

// ---------------- prep2: vp[bc][e] = Wv.v_bc + bv -> B-frags (pads=0) ------------
// grid (64,4): bx -> 8 slots of (b, c in 0..63); by -> e-group of 128
__global__ __launch_bounds__(256) void prep2_kernel(
    const float* __restrict__ v, const float* __restrict__ Wv,
    const float* __restrict__ bv, unsigned short* __restrict__ vpf) {
  __shared__ float vL[8][Dd];
  const int t = threadIdx.x;
  const int el = t & 127, half = t >> 7;
  const int e = blockIdx.y * 128 + el;
  const int sbase = blockIdx.x * 8;
  for (int i = t; i < 8 * Dd; i += 256) {
    int row = i >> 8, dd = i & (Dd - 1);
    int sg = sbase + row, bb_ = sg >> 6, cc = sg & 63;
    vL[row][dd] = (cc < 40) ? v[((size_t)bb_ * Cc + cc) * Dd + dd] : 0.f;
  }
  __syncthreads();
  const float* wrow = Wv + (size_t)e * Dd;
  float acc[4] = {0,0,0,0};
  #pragma unroll 2
  for (int dd = 0; dd < Dd; dd += 4) {
    float4 w = *(const float4*)(wrow + dd);
    #pragma unroll
    for (int si = 0; si < 4; si++) {
      float4 vv = *(const float4*)&vL[half*4 + si][dd];
      acc[si] += w.x*vv.x + w.y*vv.y + w.z*vv.z + w.w*vv.w;
    }
  }
  const float bve = bv[e];
  const int nt = e >> 4, elan = e & 15;
  #pragma unroll
  for (int si = 0; si < 4; si++) {
    int sg = sbase + half*4 + si, bb_ = sg >> 6, cc = sg & 63;
    int s = cc >> 5, gg = (cc >> 3) & 3, j = cc & 7;
    unsigned short val = (cc < 40) ? f2bf(acc[si] + bve) : (unsigned short)0;
    vpf[((((size_t)bb_*32 + nt)*2 + s)*64 + (elan + 16*gg))*8 + j] = val;
  }
}

// ---------------- main: fused logits -> softmax -> *cp -> softmax -> PV ----------
// grid 2048 (= B * N/64); 256 threads = 4 independent waves; wave owns 16 q-rows.
// Phase A: q staged via LDS (reg-staged, XOR-swizzled, double-buffered 4KB chunks).
__global__ __launch_bounds__(256, 3) void main_kernel(
    const float* __restrict__ q, const float* __restrict__ coarse,
    const unsigned short* __restrict__ abfrag,
    const unsigned short* __restrict__ vpfrag,
    const float* __restrict__ dbias, float* __restrict__ out) {
  __shared__ float4 s_q[4][2][256];             // 32 KB: per-wave dbuf swizzled q chunks
  __shared__ unsigned short s_att[4][16][72];   // 9 KB
  const int t = threadIdx.x;
  const int wave = t >> 6, lane = t & 63;
  const int r = lane & 15, g = lane >> 4;
  const int bid = blockIdx.x;
  const int b = bid >> 8, nb = bid & 255;
  const int nw = nb * 64 + wave * 16;

  // --- staging geometry: instr j covers rows 4j+sr0, 16B granule (lane&15) ---
  const int sr0 = lane >> 4;
  const int scolb = (lane & 15) << 4;
  const int swzA = scolb ^ (sr0 << 4);          // row&7 = sr0 (j even), sr0+4 (j odd)
  const float* qstage = q + (size_t)(b * Nn + nw + sr0) * Ee + ((lane & 15) << 2);
  char* const qb0 = (char*)&s_q[wave][0][0];
  char* const qb1 = (char*)&s_q[wave][1][0];
  const int wo0 = sr0*256 + 0*1024 + swzA;
  const int wo1 = sr0*256 + 1*1024 + (swzA ^ 0x40);
  const int wo2 = sr0*256 + 2*1024 + swzA;
  const int wo3 = sr0*256 + 3*1024 + (swzA ^ 0x40);
  const int rbase = r * 256;
  const int rswz = (r & 7) << 4;

  const bf16x8* abf = (const bf16x8*)abfrag + (size_t)b * 3 * 16 * 64 + lane;

  f32x4 acc0 = {0,0,0,0}, acc1 = {0,0,0,0}, acc2 = {0,0,0,0};
  float4 S0[4], S1[4];

  auto LOADC = [&](int c, float4* S) {
    #pragma unroll
    for (int j = 0; j < 4; j++)
      S[j] = *(const float4*)(qstage + (size_t)4*j*Ee + c*64);
  };
  auto DSW = [&](float4* S, char* qb) {
    *(float4*)(qb + wo0) = S[0];
    *(float4*)(qb + wo1) = S[1];
    *(float4*)(qb + wo2) = S[2];
    *(float4*)(qb + wo3) = S[3];
  };
  auto COMP = [&](int c, char* qb) {
    #pragma unroll
    for (int ksl = 0; ksl < 2; ksl++) {
      const int x = 128*ksl + 32*g;
      float4 qa = *(const float4*)(qb + rbase + ((x     ) ^ rswz));
      float4 qc = *(const float4*)(qb + rbase + ((x + 16) ^ rswz));
      bf16x8 qf;
      qf[0]=(short)f2bf(qa.x); qf[1]=(short)f2bf(qa.y);
      qf[2]=(short)f2bf(qa.z); qf[3]=(short)f2bf(qa.w);
      qf[4]=(short)f2bf(qc.x); qf[5]=(short)f2bf(qc.y);
      qf[6]=(short)f2bf(qc.z); qf[7]=(short)f2bf(qc.w);
      const int ks = 2*c + ksl;
      acc0 = __builtin_amdgcn_mfma_f32_16x16x32_bf16(abf[(0*16+ks)*64], qf, acc0, 0,0,0);
      acc1 = __builtin_amdgcn_mfma_f32_16x16x32_bf16(abf[(1*16+ks)*64], qf, acc1, 0,0,0);
      acc2 = __builtin_amdgcn_mfma_f32_16x16x32_bf16(abf[(2*16+ks)*64], qf, acc2, 0,0,0);
    }
  };

  // software pipeline, fully unrolled, wave-private (no barriers)
  LOADC(0, S0); LOADC(1, S1); DSW(S0, qb0);
  LOADC(2, S0); COMP(0, qb0); DSW(S1, qb1);
  LOADC(3, S1); COMP(1, qb1); DSW(S0, qb0);
  LOADC(4, S0); COMP(2, qb0); DSW(S1, qb1);
  LOADC(5, S1); COMP(3, qb1); DSW(S0, qb0);
  LOADC(6, S0); COMP(4, qb0); DSW(S1, qb1);
  LOADC(7, S1); COMP(5, qb1); DSW(S0, qb0);
                COMP(6, qb0); DSW(S1, qb1);
                COMP(7, qb1);

  // lane holds logits of q-row (nw+r) at classes c = 16*ct + 4*g + reg
  float L[3][4];
  #pragma unroll
  for (int rg = 0; rg < 4; rg++) {
    L[0][rg] = acc0[rg] + dbias[b*64 +  0 + 4*g + rg];
    L[1][rg] = acc1[rg] + dbias[b*64 + 16 + 4*g + rg];
    L[2][rg] = acc2[rg] + dbias[b*64 + 32 + 4*g + rg];
  }
  const bool v2 = (g < 2);   // ct==2 slots valid only when 32+4g+reg < 40

  // ---- softmax #1 over c ----
  float m1 = -3e38f;
  #pragma unroll
  for (int rg = 0; rg < 4; rg++) {
    m1 = fmaxf(m1, L[0][rg]); m1 = fmaxf(m1, L[1][rg]);
    if (v2) m1 = fmaxf(m1, L[2][rg]);
  }
  m1 = fmaxf(m1, __shfl_xor(m1, 16));
  m1 = fmaxf(m1, __shfl_xor(m1, 32));
  float p[3][4]; float s1 = 0.f;
  #pragma unroll
  for (int rg = 0; rg < 4; rg++) {
    p[0][rg] = __expf(L[0][rg] - m1); s1 += p[0][rg];
    p[1][rg] = __expf(L[1][rg] - m1); s1 += p[1][rg];
    p[2][rg] = v2 ? __expf(L[2][rg] - m1) : 0.f; s1 += p[2][rg];
  }
  s1 += __shfl_xor(s1, 16); s1 += __shfl_xor(s1, 32);
  const float inv1 = 1.0f / s1;

  // ---- cp = softmax_c(coarse_pred[b, c, n]) ----
  const float* cbase = coarse + (size_t)b * Cc * Nn + (nw + r);
  float cr[3][4];
  #pragma unroll
  for (int rg = 0; rg < 4; rg++) {
    cr[0][rg] = cbase[(size_t)( 0 + 4*g + rg) * Nn];
    cr[1][rg] = cbase[(size_t)(16 + 4*g + rg) * Nn];
    cr[2][rg] = v2 ? cbase[(size_t)(32 + 4*g + rg) * Nn] : -3e38f;
  }
  float m2 = -3e38f;
  #pragma unroll
  for (int rg = 0; rg < 4; rg++) {
    m2 = fmaxf(m2, cr[0][rg]); m2 = fmaxf(m2, cr[1][rg]);
    if (v2) m2 = fmaxf(m2, cr[2][rg]);
  }
  m2 = fmaxf(m2, __shfl_xor(m2, 16));
  m2 = fmaxf(m2, __shfl_xor(m2, 32));
  float cpv[3][4]; float s2 = 0.f;
  #pragma unroll
  for (int rg = 0; rg < 4; rg++) {
    cpv[0][rg] = __expf(cr[0][rg] - m2); s2 += cpv[0][rg];
    cpv[1][rg] = __expf(cr[1][rg] - m2); s2 += cpv[1][rg];
    cpv[2][rg] = v2 ? __expf(cr[2][rg] - m2) : 0.f; s2 += cpv[2][rg];
  }
  s2 += __shfl_xor(s2, 16); s2 += __shfl_xor(s2, 32);
  const float inv2 = 1.0f / s2;

  // ---- softmax #2 over c of (attn1 * cp) ----
  const float sc12 = inv1 * inv2;
  float w[3][4];
  float m3 = -3e38f;
  #pragma unroll
  for (int rg = 0; rg < 4; rg++) {
    w[0][rg] = p[0][rg] * cpv[0][rg] * sc12;
    w[1][rg] = p[1][rg] * cpv[1][rg] * sc12;
    w[2][rg] = v2 ? (p[2][rg] * cpv[2][rg] * sc12) : 0.f;
    m3 = fmaxf(m3, w[0][rg]); m3 = fmaxf(m3, w[1][rg]);
    if (v2) m3 = fmaxf(m3, w[2][rg]);
  }
  m3 = fmaxf(m3, __shfl_xor(m3, 16));
  m3 = fmaxf(m3, __shfl_xor(m3, 32));
  float p3[3][4]; float s3 = 0.f;
  #pragma unroll
  for (int rg = 0; rg < 4; rg++) {
    p3[0][rg] = __expf(w[0][rg] - m3); s3 += p3[0][rg];
    p3[1][rg] = __expf(w[1][rg] - m3); s3 += p3[1][rg];
    p3[2][rg] = v2 ? __expf(w[2][rg] - m3) : 0.f; s3 += p3[2][rg];
  }
  s3 += __shfl_xor(s3, 16); s3 += __shfl_xor(s3, 32);
  const float inv3 = 1.0f / s3;

  // ---- re-fragment attn2 via per-wave LDS round-trip (no barrier needed) ----
  unsigned int* srow = (unsigned int*)&s_att[wave][r][0];
  #pragma unroll
  for (int ct = 0; ct < 3; ct++) {
    srow[8*ct + 2*g + 0] = pack2(p3[ct][0]*inv3, p3[ct][1]*inv3);
    srow[8*ct + 2*g + 1] = pack2(p3[ct][2]*inv3, p3[ct][3]*inv3);
  }
  srow[24 + 2*g + 0] = 0u;   // c = 48..63 zero pad
  srow[24 + 2*g + 1] = 0u;
  asm volatile("s_waitcnt lgkmcnt(0)" ::: "memory");
  const bf16x8 pa0 = *(const bf16x8*)&s_att[wave][r][ 0 + 8*g];
  const bf16x8 pa1 = *(const bf16x8*)&s_att[wave][r][32 + 8*g];

  // ---- PV: out[16 x 512] = attn2[16 x 64] @ vp[64 x 512] ----
  const bf16x8* vpf = (const bf16x8*)vpfrag + (size_t)b * 32 * 2 * 64 + lane;
  float* outb = out + ((size_t)b * Nn + nw) * Ee;
  #pragma unroll 8
  for (int nt = 0; nt < 32; nt++) {
    bf16x8 vf0 = vpf[(nt*2 + 0)*64];
    bf16x8 vf1 = vpf[(nt*2 + 1)*64];
    f32x4 o = {0,0,0,0};
    o = __builtin_amdgcn_mfma_f32_16x16x32_bf16(pa0, vf0, o, 0,0,0);
    o = __builtin_amdgcn_mfma_f32_16x16x32_bf16(pa1, vf1, o, 0,0,0);
    #pragma unroll
    for (int rg = 0; rg < 4; rg++)
      outb[(size_t)(4*g + rg) * Ee + nt*16 + r] = o[rg];
  }
}

extern "C" void kernel_launch(void* const* d_in, const int* in_sizes, int n_in,
                              void* d_out, int out_size, void* d_ws, size_t ws_size,
                              hipStream_t stream) {
  const float* q   = (const float*)d_in[0];
  const float* k   = (const float*)d_in[1];
  const float* v   = (const float*)d_in[2];
  const float* cps = (const float*)d_in[3];
  const float* Wq  = (const float*)d_in[4];
  const float* bq  = (const float*)d_in[5];
  const float* Wk  = (const float*)d_in[6];
  const float* bk  = (const float*)d_in[7];
  const float* Wv  = (const float*)d_in[8];
  const float* bv  = (const float*)d_in[9];
  float* out = (float*)d_out;
  char* ws = (char*)d_ws;

  // ws layout (1.45 MB total)
  float*          Mt    = (float*)(ws);                       // 256*512*4 = 524288
  float*          tvec  = (float*)(ws + 524288);              // 512*4     = 2048
  float*          uvec  = (float*)(ws + 526336);              // 256*4     = 1024
  float*          bqbkp = (float*)(ws + 527360);              // 4 (pad to 1024)
  unsigned short* abf   = (unsigned short*)(ws + 528384);     // 8*3*16*64*8*2 = 393216
  unsigned short* vpf   = (unsigned short*)(ws + 528384 + 393216);  // 8*32*2*64*8*2 = 524288
  float*          dbias = (float*)(ws + 528384 + 393216 + 524288);  // 8*64*4 = 2048

  prep0_kernel<<<dim3(8, 16), 256, 0, stream>>>(Wq, Wk, bq, bk, Mt, tvec, uvec, bqbkp);
  prep2_kernel<<<dim3(64, 4), 256, 0, stream>>>(v, Wv, bv, vpf);
  prep1_kernel<<<dim3(48, 4), 256, 0, stream>>>(k, Mt, tvec, uvec, bqbkp, abf, dbias);
  main_kernel<<<dim3(2048), 256, 0, stream>>>(q, cps, abf, vpf, dbias, out);
}

// Round 3
// 215.656 us; speedup vs baseline: 1.7507x; 1.7507x over previous
//
#include <hip/hip_runtime.h>
#include <stdint.h>

#define Bb 8
#define Nn 16384
#define Cc 40
#define Ee 512
#define Dd 256

typedef __attribute__((ext_vector_type(4))) float f32x4;
typedef __attribute__((ext_vector_type(8))) short bf16x8;

__device__ __forceinline__ unsigned short f2bf(float f) {
  union { float f; uint32_t u; } x; x.f = f;
  uint32_t r = x.u + 0x7FFFu + ((x.u >> 16) & 1u);   // round-to-nearest-even
  return (unsigned short)(r >> 16);
}
__device__ __forceinline__ unsigned int pack2(float a, float b) {
  return (unsigned int)f2bf(a) | ((unsigned int)f2bf(b) << 16);
}

// ---------------- prep0: Mt[z][d][e] = sum_{f in half z} Wq[f][e]*Wk[f][d] ------
// LDS-tiled GEMM. grid (8,4,2): bx->e-tile(64), by->d-tile(64), bz->f-half(256).
// 256 threads, 4x4 accumulators per thread.
__global__ __launch_bounds__(256) void prep0_kernel(
    const float* __restrict__ Wq, const float* __restrict__ Wk,
    float* __restrict__ Mt) {
  __shared__ float WqL[64][68];   // f x e  (pad 4: 16B-aligned rows, conflict-lite)
  __shared__ float WkL[64][68];   // f x d
  const int t = threadIdx.x;
  const int te = (t & 15) * 4;
  const int td = (t >> 4) * 4;
  const int ebase = blockIdx.x * 64, dbase = blockIdx.y * 64;
  const int fbase = blockIdx.z * 256;
  f32x4 acc0 = {0,0,0,0}, acc1 = {0,0,0,0}, acc2 = {0,0,0,0}, acc3 = {0,0,0,0};
  for (int f0 = 0; f0 < 256; f0 += 64) {
    __syncthreads();
    #pragma unroll
    for (int i = 0; i < 4; i++) {
      int idx = t + i * 256;                 // 0..1023
      int row = idx >> 4, c4 = (idx & 15) * 4;
      *(float4*)&WqL[row][c4] = *(const float4*)(Wq + (size_t)(fbase + f0 + row) * Ee + ebase + c4);
      *(float4*)&WkL[row][c4] = *(const float4*)(Wk + (size_t)(fbase + f0 + row) * Dd + dbase + c4);
    }
    __syncthreads();
    #pragma unroll 8
    for (int ff = 0; ff < 64; ff++) {
      float4 a = *(const float4*)&WkL[ff][td];
      float4 b = *(const float4*)&WqL[ff][te];
      acc0[0] += a.x*b.x; acc0[1] += a.x*b.y; acc0[2] += a.x*b.z; acc0[3] += a.x*b.w;
      acc1[0] += a.y*b.x; acc1[1] += a.y*b.y; acc1[2] += a.y*b.z; acc1[3] += a.y*b.w;
      acc2[0] += a.z*b.x; acc2[1] += a.z*b.y; acc2[2] += a.z*b.z; acc2[3] += a.z*b.w;
      acc3[0] += a.w*b.x; acc3[1] += a.w*b.y; acc3[2] += a.w*b.z; acc3[3] += a.w*b.w;
    }
  }
  float* mt = Mt + (size_t)blockIdx.z * 131072;
  *(f32x4*)&mt[(size_t)(dbase + td + 0) * Ee + ebase + te] = acc0;
  *(f32x4*)&mt[(size_t)(dbase + td + 1) * Ee + ebase + te] = acc1;
  *(f32x4*)&mt[(size_t)(dbase + td + 2) * Ee + ebase + te] = acc2;
  *(f32x4*)&mt[(size_t)(dbase + td + 3) * Ee + ebase + te] = acc3;
}

// ---------------- prep0b: tvec[e]=Wq^T bk; uvec[d]=Wk^T bq; bqbk=bq.bk ----------
// grid 3 blocks x 256 threads
__global__ __launch_bounds__(256) void prep0b_kernel(
    const float* __restrict__ Wq, const float* __restrict__ Wk,
    const float* __restrict__ bq, const float* __restrict__ bk,
    float* __restrict__ tvec, float* __restrict__ uvec, float* __restrict__ bqbk) {
  const int t = threadIdx.x, bx = blockIdx.x;
  if (bx < 2) {
    const int e = bx * 256 + t;
    float s = 0.f;
    #pragma unroll 8
    for (int f = 0; f < Ee; f++) s += Wq[(size_t)f * Ee + e] * bk[f];
    tvec[e] = s;
  } else {
    const int d = t;
    float s = 0.f;
    #pragma unroll 8
    for (int f = 0; f < Ee; f++) s += Wk[(size_t)f * Dd + d] * bq[f];
    uvec[d] = s;
    __shared__ float red[256];
    float p = 0.f;
    for (int f = t; f < Ee; f += 256) p += bq[f] * bk[f];
    red[t] = p; __syncthreads();
    #pragma unroll
    for (int off = 128; off > 0; off >>= 1) {
      if (t < off) red[t] += red[t + off];
      __syncthreads();
    }
    if (t == 0) bqbk[0] = red[0];
  }
}

// ---------------- prep1: G[e][bc] = scale*((Mt0+Mt1).k_bc + t[e]) -> A-frags;
//                  dbias[b*64+c] = scale*(u.k_bc + bqbk) ----------------
// grid (48,4): bx -> 8 slots of (b, c in 0..47); by -> e-group of 128
__global__ __launch_bounds__(256) void prep1_kernel(
    const float* __restrict__ k, const float* __restrict__ Mt,
    const float* __restrict__ tvec, const float* __restrict__ uvec,
    const float* __restrict__ bqbk, unsigned short* __restrict__ abf,
    float* __restrict__ dbias) {
  __shared__ float kL[8][Dd];
  const int t = threadIdx.x;
  const int el = t & 127, half = t >> 7;
  const int e = blockIdx.y * 128 + el;
  const int sbase = blockIdx.x * 8;
  for (int i = t; i < 8 * Dd; i += 256) {
    int row = i >> 8, dd = i & (Dd - 1);
    int sg = sbase + row, bb_ = sg / 48, cc = sg % 48;
    kL[row][dd] = (cc < 40) ? k[((size_t)bb_ * Cc + cc) * Dd + dd] : 0.f;
  }
  __syncthreads();
  float acc[4] = {0,0,0,0};
  float db[4]  = {0,0,0,0};
  #pragma unroll 4
  for (int d = 0; d < Dd; d++) {
    float mt = Mt[(size_t)d * Ee + e] + Mt[131072 + (size_t)d * Ee + e];
    float ud = uvec[d];
    #pragma unroll
    for (int si = 0; si < 4; si++) {
      float kv = kL[half*4 + si][d];
      acc[si] += mt * kv;
      db[si]  += ud * kv;
    }
  }
  const float scale = 0.044194173824159216f;  // 1/sqrt(512)
  const float te = tvec[e];
  const float bqbkv = bqbk[0];
  const int ks = e >> 5, gg = (e >> 3) & 3, j = e & 7;
  #pragma unroll
  for (int si = 0; si < 4; si++) {
    int sg = sbase + half*4 + si, bb_ = sg / 48, cc = sg % 48;
    int ct = cc >> 4, lane16 = (cc & 15) + 16*gg;
    unsigned short val = (cc < 40) ? f2bf(scale * (acc[si] + te)) : (unsigned short)0;
    abf[((((size_t)bb_*3 + ct)*16 + ks)*64 + lane16)*8 + j] = val;
    if (el == 0) dbias[bb_*64 + cc] = (cc < 40) ? scale * (db[si] + bqbkv) : 0.f;
  }
}

// ---------------- prep2: vp[bc][e] = Wv.v_bc + bv -> B-frags (pads=0) ------------
// grid (64,4): bx -> 8 slots of (b, c in 0..63); by -> e-group of 128
__global__ __launch_bounds__(256) void prep2_kernel(
    const float* __restrict__ v, const float* __restrict__ Wv,
    const float* __restrict__ bv, unsigned short* __restrict__ vpf) {
  __shared__ float vL[8][Dd];
  const int t = threadIdx.x;
  const int el = t & 127, half = t >> 7;
  const int e = blockIdx.y * 128 + el;
  const int sbase = blockIdx.x * 8;
  for (int i = t; i < 8 * Dd; i += 256) {
    int row = i >> 8, dd = i & (Dd - 1);
    int sg = sbase + row, bb_ = sg >> 6, cc = sg & 63;
    vL[row][dd] = (cc < 40) ? v[((size_t)bb_ * Cc + cc) * Dd + dd] : 0.f;
  }
  __syncthreads();
  const float* wrow = Wv + (size_t)e * Dd;
  float acc[4] = {0,0,0,0};
  #pragma unroll 2
  for (int dd = 0; dd < Dd; dd += 4) {
    float4 w = *(const float4*)(wrow + dd);
    #pragma unroll
    for (int si = 0; si < 4; si++) {
      float4 vv = *(const float4*)&vL[half*4 + si][dd];
      acc[si] += w.x*vv.x + w.y*vv.y + w.z*vv.z + w.w*vv.w;
    }
  }
  const float bve = bv[e];
  const int nt = e >> 4, elan = e & 15;
  #pragma unroll
  for (int si = 0; si < 4; si++) {
    int sg = sbase + half*4 + si, bb_ = sg >> 6, cc = sg & 63;
    int s = cc >> 5, gg = (cc >> 3) & 3, j = cc & 7;
    unsigned short val = (cc < 40) ? f2bf(acc[si] + bve) : (unsigned short)0;
    vpf[((((size_t)bb_*32 + nt)*2 + s)*64 + (elan + 16*gg))*8 + j] = val;
  }
}

// ---------------- main: fused logits -> softmax -> *cp -> softmax -> PV ----------
// grid 2048 (= B * N/64); 256 threads = 4 independent waves; wave owns 16 q-rows.
// Phase A: q staged via LDS (reg-staged, XOR-swizzled, double-buffered 4KB chunks).
__global__ __launch_bounds__(256, 3) void main_kernel(
    const float* __restrict__ q, const float* __restrict__ coarse,
    const unsigned short* __restrict__ abfrag,
    const unsigned short* __restrict__ vpfrag,
    const float* __restrict__ dbias, float* __restrict__ out) {
  __shared__ float4 s_q[4][2][256];             // 32 KB: per-wave dbuf swizzled q chunks
  __shared__ unsigned short s_att[4][16][72];   // 9 KB
  const int t = threadIdx.x;
  const int wave = t >> 6, lane = t & 63;
  const int r = lane & 15, g = lane >> 4;
  const int bid = blockIdx.x;
  const int b = bid >> 8, nb = bid & 255;
  const int nw = nb * 64 + wave * 16;

  // --- staging geometry: instr j covers rows 4j+sr0, 16B granule (lane&15) ---
  const int sr0 = lane >> 4;
  const int scolb = (lane & 15) << 4;
  const int swzA = scolb ^ (sr0 << 4);          // row&7 = sr0 (j even), sr0+4 (j odd)
  const float* qstage = q + (size_t)(b * Nn + nw + sr0) * Ee + ((lane & 15) << 2);
  char* const qb0 = (char*)&s_q[wave][0][0];
  char* const qb1 = (char*)&s_q[wave][1][0];
  const int wo0 = sr0*256 + 0*1024 + swzA;
  const int wo1 = sr0*256 + 1*1024 + (swzA ^ 0x40);
  const int wo2 = sr0*256 + 2*1024 + swzA;
  const int wo3 = sr0*256 + 3*1024 + (swzA ^ 0x40);
  const int rbase = r * 256;
  const int rswz = (r & 7) << 4;

  const bf16x8* abf = (const bf16x8*)abfrag + (size_t)b * 3 * 16 * 64 + lane;

  f32x4 acc0 = {0,0,0,0}, acc1 = {0,0,0,0}, acc2 = {0,0,0,0};
  float4 S0[4], S1[4];

  auto LOADC = [&](int c, float4* S) {
    #pragma unroll
    for (int j = 0; j < 4; j++)
      S[j] = *(const float4*)(qstage + (size_t)4*j*Ee + c*64);
  };
  auto DSW = [&](float4* S, char* qb) {
    *(float4*)(qb + wo0) = S[0];
    *(float4*)(qb + wo1) = S[1];
    *(float4*)(qb + wo2) = S[2];
    *(float4*)(qb + wo3) = S[3];
  };
  auto COMP = [&](int c, char* qb) {
    #pragma unroll
    for (int ksl = 0; ksl < 2; ksl++) {
      const int x = 128*ksl + 32*g;
      float4 qa = *(const float4*)(qb + rbase + ((x     ) ^ rswz));
      float4 qc = *(const float4*)(qb + rbase + ((x + 16) ^ rswz));
      bf16x8 qf;
      qf[0]=(short)f2bf(qa.x); qf[1]=(short)f2bf(qa.y);
      qf[2]=(short)f2bf(qa.z); qf[3]=(short)f2bf(qa.w);
      qf[4]=(short)f2bf(qc.x); qf[5]=(short)f2bf(qc.y);
      qf[6]=(short)f2bf(qc.z); qf[7]=(short)f2bf(qc.w);
      const int ks = 2*c + ksl;
      acc0 = __builtin_amdgcn_mfma_f32_16x16x32_bf16(abf[(0*16+ks)*64], qf, acc0, 0,0,0);
      acc1 = __builtin_amdgcn_mfma_f32_16x16x32_bf16(abf[(1*16+ks)*64], qf, acc1, 0,0,0);
      acc2 = __builtin_amdgcn_mfma_f32_16x16x32_bf16(abf[(2*16+ks)*64], qf, acc2, 0,0,0);
    }
  };

  // software pipeline, fully unrolled, wave-private (no barriers)
  LOADC(0, S0); LOADC(1, S1); DSW(S0, qb0);
  LOADC(2, S0); COMP(0, qb0); DSW(S1, qb1);
  LOADC(3, S1); COMP(1, qb1); DSW(S0, qb0);
  LOADC(4, S0); COMP(2, qb0); DSW(S1, qb1);
  LOADC(5, S1); COMP(3, qb1); DSW(S0, qb0);
  LOADC(6, S0); COMP(4, qb0); DSW(S1, qb1);
  LOADC(7, S1); COMP(5, qb1); DSW(S0, qb0);
                COMP(6, qb0); DSW(S1, qb1);
                COMP(7, qb1);

  // lane holds logits of q-row (nw+r) at classes c = 16*ct + 4*g + reg
  float L[3][4];
  #pragma unroll
  for (int rg = 0; rg < 4; rg++) {
    L[0][rg] = acc0[rg] + dbias[b*64 +  0 + 4*g + rg];
    L[1][rg] = acc1[rg] + dbias[b*64 + 16 + 4*g + rg];
    L[2][rg] = acc2[rg] + dbias[b*64 + 32 + 4*g + rg];
  }
  const bool v2 = (g < 2);   // ct==2 slots valid only when 32+4g+reg < 40

  // ---- softmax #1 over c ----
  float m1 = -3e38f;
  #pragma unroll
  for (int rg = 0; rg < 4; rg++) {
    m1 = fmaxf(m1, L[0][rg]); m1 = fmaxf(m1, L[1][rg]);
    if (v2) m1 = fmaxf(m1, L[2][rg]);
  }
  m1 = fmaxf(m1, __shfl_xor(m1, 16));
  m1 = fmaxf(m1, __shfl_xor(m1, 32));
  float p[3][4]; float s1 = 0.f;
  #pragma unroll
  for (int rg = 0; rg < 4; rg++) {
    p[0][rg] = __expf(L[0][rg] - m1); s1 += p[0][rg];
    p[1][rg] = __expf(L[1][rg] - m1); s1 += p[1][rg];
    p[2][rg] = v2 ? __expf(L[2][rg] - m1) : 0.f; s1 += p[2][rg];
  }
  s1 += __shfl_xor(s1, 16); s1 += __shfl_xor(s1, 32);
  const float inv1 = 1.0f / s1;

  // ---- cp = softmax_c(coarse_pred[b, c, n]) ----
  const float* cbase = coarse + (size_t)b * Cc * Nn + (nw + r);
  float cr[3][4];
  #pragma unroll
  for (int rg = 0; rg < 4; rg++) {
    cr[0][rg] = cbase[(size_t)( 0 + 4*g + rg) * Nn];
    cr[1][rg] = cbase[(size_t)(16 + 4*g + rg) * Nn];
    cr[2][rg] = v2 ? cbase[(size_t)(32 + 4*g + rg) * Nn] : -3e38f;
  }
  float m2 = -3e38f;
  #pragma unroll
  for (int rg = 0; rg < 4; rg++) {
    m2 = fmaxf(m2, cr[0][rg]); m2 = fmaxf(m2, cr[1][rg]);
    if (v2) m2 = fmaxf(m2, cr[2][rg]);
  }
  m2 = fmaxf(m2, __shfl_xor(m2, 16));
  m2 = fmaxf(m2, __shfl_xor(m2, 32));
  float cpv[3][4]; float s2 = 0.f;
  #pragma unroll
  for (int rg = 0; rg < 4; rg++) {
    cpv[0][rg] = __expf(cr[0][rg] - m2); s2 += cpv[0][rg];
    cpv[1][rg] = __expf(cr[1][rg] - m2); s2 += cpv[1][rg];
    cpv[2][rg] = v2 ? __expf(cr[2][rg] - m2) : 0.f; s2 += cpv[2][rg];
  }
  s2 += __shfl_xor(s2, 16); s2 += __shfl_xor(s2, 32);
  const float inv2 = 1.0f / s2;

  // ---- softmax #2 over c of (attn1 * cp) ----
  const float sc12 = inv1 * inv2;
  float w[3][4];
  float m3 = -3e38f;
  #pragma unroll
  for (int rg = 0; rg < 4; rg++) {
    w[0][rg] = p[0][rg] * cpv[0][rg] * sc12;
    w[1][rg] = p[1][rg] * cpv[1][rg] * sc12;
    w[2][rg] = v2 ? (p[2][rg] * cpv[2][rg] * sc12) : 0.f;
    m3 = fmaxf(m3, w[0][rg]); m3 = fmaxf(m3, w[1][rg]);
    if (v2) m3 = fmaxf(m3, w[2][rg]);
  }
  m3 = fmaxf(m3, __shfl_xor(m3, 16));
  m3 = fmaxf(m3, __shfl_xor(m3, 32));
  float p3[3][4]; float s3 = 0.f;
  #pragma unroll
  for (int rg = 0; rg < 4; rg++) {
    p3[0][rg] = __expf(w[0][rg] - m3); s3 += p3[0][rg];
    p3[1][rg] = __expf(w[1][rg] - m3); s3 += p3[1][rg];
    p3[2][rg] = v2 ? __expf(w[2][rg] - m3) : 0.f; s3 += p3[2][rg];
  }
  s3 += __shfl_xor(s3, 16); s3 += __shfl_xor(s3, 32);
  const float inv3 = 1.0f / s3;

  // ---- re-fragment attn2 via per-wave LDS round-trip (no barrier needed) ----
  unsigned int* srow = (unsigned int*)&s_att[wave][r][0];
  #pragma unroll
  for (int ct = 0; ct < 3; ct++) {
    srow[8*ct + 2*g + 0] = pack2(p3[ct][0]*inv3, p3[ct][1]*inv3);
    srow[8*ct + 2*g + 1] = pack2(p3[ct][2]*inv3, p3[ct][3]*inv3);
  }
  srow[24 + 2*g + 0] = 0u;   // c = 48..63 zero pad
  srow[24 + 2*g + 1] = 0u;
  asm volatile("s_waitcnt lgkmcnt(0)" ::: "memory");
  const bf16x8 pa0 = *(const bf16x8*)&s_att[wave][r][ 0 + 8*g];
  const bf16x8 pa1 = *(const bf16x8*)&s_att[wave][r][32 + 8*g];

  // ---- PV: out[16 x 512] = attn2[16 x 64] @ vp[64 x 512] ----
  const bf16x8* vpf = (const bf16x8*)vpfrag + (size_t)b * 32 * 2 * 64 + lane;
  float* outb = out + ((size_t)b * Nn + nw) * Ee;
  #pragma unroll 8
  for (int nt = 0; nt < 32; nt++) {
    bf16x8 vf0 = vpf[(nt*2 + 0)*64];
    bf16x8 vf1 = vpf[(nt*2 + 1)*64];
    f32x4 o = {0,0,0,0};
    o = __builtin_amdgcn_mfma_f32_16x16x32_bf16(pa0, vf0, o, 0,0,0);
    o = __builtin_amdgcn_mfma_f32_16x16x32_bf16(pa1, vf1, o, 0,0,0);
    #pragma unroll
    for (int rg = 0; rg < 4; rg++)
      outb[(size_t)(4*g + rg) * Ee + nt*16 + r] = o[rg];
  }
}

extern "C" void kernel_launch(void* const* d_in, const int* in_sizes, int n_in,
                              void* d_out, int out_size, void* d_ws, size_t ws_size,
                              hipStream_t stream) {
  const float* q   = (const float*)d_in[0];
  const float* k   = (const float*)d_in[1];
  const float* v   = (const float*)d_in[2];
  const float* cps = (const float*)d_in[3];
  const float* Wq  = (const float*)d_in[4];
  const float* bq  = (const float*)d_in[5];
  const float* Wk  = (const float*)d_in[6];
  const float* bk  = (const float*)d_in[7];
  const float* Wv  = (const float*)d_in[8];
  const float* bv  = (const float*)d_in[9];
  float* out = (float*)d_out;
  char* ws = (char*)d_ws;

  // ws layout (~1.97 MB total)
  float*          Mt    = (float*)(ws);                        // 2*256*512*4 = 1048576
  float*          tvec  = (float*)(ws + 1048576);              // 512*4  = 2048
  float*          uvec  = (float*)(ws + 1050624);              // 256*4  = 1024
  float*          bqbkp = (float*)(ws + 1051648);              // 4 (pad to 1024)
  unsigned short* abf   = (unsigned short*)(ws + 1052672);     // 8*3*16*64*8*2 = 393216
  unsigned short* vpf   = (unsigned short*)(ws + 1052672 + 393216);          // 524288
  float*          dbias = (float*)(ws + 1052672 + 393216 + 524288);          // 2048

  prep0_kernel <<<dim3(8, 4, 2), 256, 0, stream>>>(Wq, Wk, Mt);
  prep0b_kernel<<<dim3(3),       256, 0, stream>>>(Wq, Wk, bq, bk, tvec, uvec, bqbkp);
  prep2_kernel <<<dim3(64, 4),   256, 0, stream>>>(v, Wv, bv, vpf);
  prep1_kernel <<<dim3(48, 4),   256, 0, stream>>>(k, Mt, tvec, uvec, bqbkp, abf, dbias);
  main_kernel  <<<dim3(2048),    256, 0, stream>>>(q, cps, abf, vpf, dbias, out);
}

// Round 4
// 206.134 us; speedup vs baseline: 1.8316x; 1.0462x over previous
//
#include <hip/hip_runtime.h>
#include <stdint.h>

#define Bb 8
#define Nn 16384
#define Cc 40
#define Ee 512
#define Dd 256

typedef __attribute__((ext_vector_type(4))) float f32x4;
typedef __attribute__((ext_vector_type(8))) short bf16x8;

__device__ __forceinline__ unsigned short f2bf(float f) {
  union { float f; uint32_t u; } x; x.f = f;
  uint32_t r = x.u + 0x7FFFu + ((x.u >> 16) & 1u);   // round-to-nearest-even
  return (unsigned short)(r >> 16);
}
__device__ __forceinline__ unsigned int pack2(float a, float b) {
  return (unsigned int)f2bf(a) | ((unsigned int)f2bf(b) << 16);
}

// ---------------- prepA: Mt[z][d][e] = sum_{f half z} Wq[f][e]*Wk[f][d];
//                  plus (bx==8,bz==0): tvec/uvec/bqbk bias vectors ----------------
// grid (9,4,2), 256 thr.
__global__ __launch_bounds__(256) void prepA_kernel(
    const float* __restrict__ Wq, const float* __restrict__ Wk,
    const float* __restrict__ bq, const float* __restrict__ bk,
    float* __restrict__ Mt, float* __restrict__ tvec,
    float* __restrict__ uvec, float* __restrict__ bqbk) {
  const int t = threadIdx.x;
  if (blockIdx.x == 8) {
    if (blockIdx.z != 0) return;
    const int by = blockIdx.y;
    if (by < 2) {
      const int e = by * 256 + t;
      float s = 0.f;
      #pragma unroll 8
      for (int f = 0; f < Ee; f++) s += Wq[(size_t)f * Ee + e] * bk[f];
      tvec[e] = s;
    } else if (by == 2) {
      const int d = t;
      float s = 0.f;
      #pragma unroll 8
      for (int f = 0; f < Ee; f++) s += Wk[(size_t)f * Dd + d] * bq[f];
      uvec[d] = s;
    } else {
      __shared__ float red[256];
      float p = 0.f;
      for (int f = t; f < Ee; f += 256) p += bq[f] * bk[f];
      red[t] = p; __syncthreads();
      #pragma unroll
      for (int off = 128; off > 0; off >>= 1) {
        if (t < off) red[t] += red[t + off];
        __syncthreads();
      }
      if (t == 0) bqbk[0] = red[0];
    }
    return;
  }
  __shared__ float WqL[64][68];
  __shared__ float WkL[64][68];
  const int te = (t & 15) * 4;
  const int td = (t >> 4) * 4;
  const int ebase = blockIdx.x * 64, dbase = blockIdx.y * 64;
  const int fbase = blockIdx.z * 256;
  f32x4 acc0 = {0,0,0,0}, acc1 = {0,0,0,0}, acc2 = {0,0,0,0}, acc3 = {0,0,0,0};
  for (int f0 = 0; f0 < 256; f0 += 64) {
    __syncthreads();
    #pragma unroll
    for (int i = 0; i < 4; i++) {
      int idx = t + i * 256;
      int row = idx >> 4, c4 = (idx & 15) * 4;
      *(float4*)&WqL[row][c4] = *(const float4*)(Wq + (size_t)(fbase + f0 + row) * Ee + ebase + c4);
      *(float4*)&WkL[row][c4] = *(const float4*)(Wk + (size_t)(fbase + f0 + row) * Dd + dbase + c4);
    }
    __syncthreads();
    #pragma unroll 8
    for (int ff = 0; ff < 64; ff++) {
      float4 a = *(const float4*)&WkL[ff][td];
      float4 b = *(const float4*)&WqL[ff][te];
      acc0[0] += a.x*b.x; acc0[1] += a.x*b.y; acc0[2] += a.x*b.z; acc0[3] += a.x*b.w;
      acc1[0] += a.y*b.x; acc1[1] += a.y*b.y; acc1[2] += a.y*b.z; acc1[3] += a.y*b.w;
      acc2[0] += a.z*b.x; acc2[1] += a.z*b.y; acc2[2] += a.z*b.z; acc2[3] += a.z*b.w;
      acc3[0] += a.w*b.x; acc3[1] += a.w*b.y; acc3[2] += a.w*b.z; acc3[3] += a.w*b.w;
    }
  }
  float* mt = Mt + (size_t)blockIdx.z * 131072;
  *(f32x4*)&mt[(size_t)(dbase + td + 0) * Ee + ebase + te] = acc0;
  *(f32x4*)&mt[(size_t)(dbase + td + 1) * Ee + ebase + te] = acc1;
  *(f32x4*)&mt[(size_t)(dbase + td + 2) * Ee + ebase + te] = acc2;
  *(f32x4*)&mt[(size_t)(dbase + td + 3) * Ee + ebase + te] = acc3;
}

// ---------------- prepB: bx<48 -> A-frags(G)+dbias; bx>=48 -> B-frags(vp) --------
// grid (112,4), 256 thr.
__global__ __launch_bounds__(256) void prepB_kernel(
    const float* __restrict__ k, const float* __restrict__ v,
    const float* __restrict__ Wv, const float* __restrict__ bv,
    const float* __restrict__ Mt, const float* __restrict__ tvec,
    const float* __restrict__ uvec, const float* __restrict__ bqbk,
    unsigned short* __restrict__ abf, unsigned short* __restrict__ vpf,
    float* __restrict__ dbias) {
  __shared__ float xL[8][Dd];
  const int t = threadIdx.x;
  const int el = t & 127, half = t >> 7;
  const int e = blockIdx.y * 128 + el;

  if (blockIdx.x < 48) {
    const int sbase = blockIdx.x * 8;
    for (int i = t; i < 8 * Dd; i += 256) {
      int row = i >> 8, dd = i & (Dd - 1);
      int sg = sbase + row, bb_ = sg / 48, cc = sg % 48;
      xL[row][dd] = (cc < 40) ? k[((size_t)bb_ * Cc + cc) * Dd + dd] : 0.f;
    }
    __syncthreads();
    float acc[4] = {0,0,0,0};
    float db[4]  = {0,0,0,0};
    #pragma unroll 4
    for (int d = 0; d < Dd; d++) {
      float mt = Mt[(size_t)d * Ee + e] + Mt[131072 + (size_t)d * Ee + e];
      float ud = uvec[d];
      #pragma unroll
      for (int si = 0; si < 4; si++) {
        float kv = xL[half*4 + si][d];
        acc[si] += mt * kv;
        db[si]  += ud * kv;
      }
    }
    const float scale = 0.044194173824159216f;  // 1/sqrt(512)
    const float te = tvec[e];
    const float bqbkv = bqbk[0];
    const int ks = e >> 5, gg = (e >> 3) & 3, j = e & 7;
    #pragma unroll
    for (int si = 0; si < 4; si++) {
      int sg = sbase + half*4 + si, bb_ = sg / 48, cc = sg % 48;
      int ct = cc >> 4, lane16 = (cc & 15) + 16*gg;
      unsigned short val = (cc < 40) ? f2bf(scale * (acc[si] + te)) : (unsigned short)0;
      abf[((((size_t)bb_*3 + ct)*16 + ks)*64 + lane16)*8 + j] = val;
      if (el == 0) dbias[bb_*64 + cc] = (cc < 40) ? scale * (db[si] + bqbkv) : 0.f;
    }
  } else {
    const int sbase = (blockIdx.x - 48) * 8;
    for (int i = t; i < 8 * Dd; i += 256) {
      int row = i >> 8, dd = i & (Dd - 1);
      int sg = sbase + row, bb_ = sg >> 6, cc = sg & 63;
      xL[row][dd] = (cc < 40) ? v[((size_t)bb_ * Cc + cc) * Dd + dd] : 0.f;
    }
    __syncthreads();
    const float* wrow = Wv + (size_t)e * Dd;
    float acc[4] = {0,0,0,0};
    #pragma unroll 2
    for (int dd = 0; dd < Dd; dd += 4) {
      float4 w = *(const float4*)(wrow + dd);
      #pragma unroll
      for (int si = 0; si < 4; si++) {
        float4 vv = *(const float4*)&xL[half*4 + si][dd];
        acc[si] += w.x*vv.x + w.y*vv.y + w.z*vv.z + w.w*vv.w;
      }
    }
    const float bve = bv[e];
    const int nt = e >> 4, elan = e & 15;
    #pragma unroll
    for (int si = 0; si < 4; si++) {
      int sg = sbase + half*4 + si, bb_ = sg >> 6, cc = sg & 63;
      int s = cc >> 5, gg = (cc >> 3) & 3, j = cc & 7;
      unsigned short val = (cc < 40) ? f2bf(acc[si] + bve) : (unsigned short)0;
      vpf[((((size_t)bb_*32 + nt)*2 + s)*64 + (elan + 16*gg))*8 + j] = val;
    }
  }
}

// ---------------- main: fused logits -> softmax -> *cp -> softmax -> PV ----------
// grid 8192 single-wave blocks (= B * N/16); wave owns 16 q-rows.
// Direct global->reg q loads, depth-2 chunk prefetch (chunk = 4 K-steps).
__global__ __launch_bounds__(64, 4) void main_kernel(
    const float* __restrict__ q, const float* __restrict__ coarse,
    const unsigned short* __restrict__ abfrag,
    const unsigned short* __restrict__ vpfrag,
    const float* __restrict__ dbias, float* __restrict__ out) {
  __shared__ unsigned short s_att[16][72];
  const int lane = threadIdx.x;
  const int r = lane & 15, g = lane >> 4;
  const int bid = blockIdx.x;
  const int b = bid >> 10;
  const int nw = (bid & 1023) << 4;
  const float* qrow = q + ((size_t)b * Nn + nw + r) * Ee + 8 * g;
  const bf16x8* abf = (const bf16x8*)abfrag + (size_t)b * 3 * 16 * 64 + lane;
  const bool v2 = (g < 2);

  f32x4 acc0 = {0,0,0,0}, acc1 = {0,0,0,0}, acc2 = {0,0,0,0};
  float4 A0[8], A1[8];

  // ---- issue chunks 0,1 of q (16 independent float4 loads) ----
  #pragma unroll
  for (int j = 0; j < 4; j++) {
    A0[2*j]   = *(const float4*)(qrow + 32*j);
    A0[2*j+1] = *(const float4*)(qrow + 32*j + 4);
  }
  #pragma unroll
  for (int j = 0; j < 4; j++) {
    A1[2*j]   = *(const float4*)(qrow + 128 + 32*j);
    A1[2*j+1] = *(const float4*)(qrow + 128 + 32*j + 4);
  }

  // ---- hoisted small loads: coarse_pred row + dbias (hide under phase A) ----
  const float* cbase = coarse + (size_t)b * Cc * Nn + (nw + r);
  float cr[3][4];
  #pragma unroll
  for (int rg = 0; rg < 4; rg++) {
    cr[0][rg] = cbase[(size_t)( 0 + 4*g + rg) * Nn];
    cr[1][rg] = cbase[(size_t)(16 + 4*g + rg) * Nn];
    cr[2][rg] = v2 ? cbase[(size_t)(32 + 4*g + rg) * Nn] : -3e38f;
  }
  float4 db0 = *(const float4*)(dbias + b*64 +  0 + 4*g);
  float4 db1 = *(const float4*)(dbias + b*64 + 16 + 4*g);
  float4 db2 = *(const float4*)(dbias + b*64 + 32 + 4*g);

  auto COMP = [&](const float4* A, int c) {
    #pragma unroll
    for (int j = 0; j < 4; j++) {
      float4 qa = A[2*j], qc = A[2*j+1];
      bf16x8 qf;
      qf[0]=(short)f2bf(qa.x); qf[1]=(short)f2bf(qa.y);
      qf[2]=(short)f2bf(qa.z); qf[3]=(short)f2bf(qa.w);
      qf[4]=(short)f2bf(qc.x); qf[5]=(short)f2bf(qc.y);
      qf[6]=(short)f2bf(qc.z); qf[7]=(short)f2bf(qc.w);
      const int ks = 4*c + j;
      acc0 = __builtin_amdgcn_mfma_f32_16x16x32_bf16(abf[(0*16+ks)*64], qf, acc0, 0,0,0);
      acc1 = __builtin_amdgcn_mfma_f32_16x16x32_bf16(abf[(1*16+ks)*64], qf, acc1, 0,0,0);
      acc2 = __builtin_amdgcn_mfma_f32_16x16x32_bf16(abf[(2*16+ks)*64], qf, acc2, 0,0,0);
    }
  };

  COMP(A0, 0);
  #pragma unroll
  for (int j = 0; j < 4; j++) {          // chunk 2 -> A0
    A0[2*j]   = *(const float4*)(qrow + 256 + 32*j);
    A0[2*j+1] = *(const float4*)(qrow + 256 + 32*j + 4);
  }
  COMP(A1, 1);
  #pragma unroll
  for (int j = 0; j < 4; j++) {          // chunk 3 -> A1
    A1[2*j]   = *(const float4*)(qrow + 384 + 32*j);
    A1[2*j+1] = *(const float4*)(qrow + 384 + 32*j + 4);
  }
  COMP(A0, 2);
  COMP(A1, 3);

  // lane holds logits of q-row (nw+r) at classes c = 16*ct + 4*g + reg
  float L[3][4];
  #pragma unroll
  for (int rg = 0; rg < 4; rg++) {
    L[0][rg] = acc0[rg] + ((const float*)&db0)[rg];
    L[1][rg] = acc1[rg] + ((const float*)&db1)[rg];
    L[2][rg] = acc2[rg] + ((const float*)&db2)[rg];
  }

  // ---- softmax #1 over c ----
  float m1 = -3e38f;
  #pragma unroll
  for (int rg = 0; rg < 4; rg++) {
    m1 = fmaxf(m1, L[0][rg]); m1 = fmaxf(m1, L[1][rg]);
    if (v2) m1 = fmaxf(m1, L[2][rg]);
  }
  m1 = fmaxf(m1, __shfl_xor(m1, 16));
  m1 = fmaxf(m1, __shfl_xor(m1, 32));
  float p[3][4]; float s1 = 0.f;
  #pragma unroll
  for (int rg = 0; rg < 4; rg++) {
    p[0][rg] = __expf(L[0][rg] - m1); s1 += p[0][rg];
    p[1][rg] = __expf(L[1][rg] - m1); s1 += p[1][rg];
    p[2][rg] = v2 ? __expf(L[2][rg] - m1) : 0.f; s1 += p[2][rg];
  }
  s1 += __shfl_xor(s1, 16); s1 += __shfl_xor(s1, 32);
  const float inv1 = 1.0f / s1;

  // ---- cp = softmax_c(coarse_pred) ----
  float m2 = -3e38f;
  #pragma unroll
  for (int rg = 0; rg < 4; rg++) {
    m2 = fmaxf(m2, cr[0][rg]); m2 = fmaxf(m2, cr[1][rg]);
    if (v2) m2 = fmaxf(m2, cr[2][rg]);
  }
  m2 = fmaxf(m2, __shfl_xor(m2, 16));
  m2 = fmaxf(m2, __shfl_xor(m2, 32));
  float cpv[3][4]; float s2 = 0.f;
  #pragma unroll
  for (int rg = 0; rg < 4; rg++) {
    cpv[0][rg] = __expf(cr[0][rg] - m2); s2 += cpv[0][rg];
    cpv[1][rg] = __expf(cr[1][rg] - m2); s2 += cpv[1][rg];
    cpv[2][rg] = v2 ? __expf(cr[2][rg] - m2) : 0.f; s2 += cpv[2][rg];
  }
  s2 += __shfl_xor(s2, 16); s2 += __shfl_xor(s2, 32);
  const float inv2 = 1.0f / s2;

  // ---- softmax #2 over c of (attn1 * cp) ----
  const float sc12 = inv1 * inv2;
  float w[3][4];
  float m3 = -3e38f;
  #pragma unroll
  for (int rg = 0; rg < 4; rg++) {
    w[0][rg] = p[0][rg] * cpv[0][rg] * sc12;
    w[1][rg] = p[1][rg] * cpv[1][rg] * sc12;
    w[2][rg] = v2 ? (p[2][rg] * cpv[2][rg] * sc12) : 0.f;
    m3 = fmaxf(m3, w[0][rg]); m3 = fmaxf(m3, w[1][rg]);
    if (v2) m3 = fmaxf(m3, w[2][rg]);
  }
  m3 = fmaxf(m3, __shfl_xor(m3, 16));
  m3 = fmaxf(m3, __shfl_xor(m3, 32));
  float p3[3][4]; float s3 = 0.f;
  #pragma unroll
  for (int rg = 0; rg < 4; rg++) {
    p3[0][rg] = __expf(w[0][rg] - m3); s3 += p3[0][rg];
    p3[1][rg] = __expf(w[1][rg] - m3); s3 += p3[1][rg];
    p3[2][rg] = v2 ? __expf(w[2][rg] - m3) : 0.f; s3 += p3[2][rg];
  }
  s3 += __shfl_xor(s3, 16); s3 += __shfl_xor(s3, 32);
  const float inv3 = 1.0f / s3;

  // ---- re-fragment attn2 via LDS round-trip (single wave: in-order DS) ----
  unsigned int* srow = (unsigned int*)&s_att[r][0];
  #pragma unroll
  for (int ct = 0; ct < 3; ct++) {
    srow[8*ct + 2*g + 0] = pack2(p3[ct][0]*inv3, p3[ct][1]*inv3);
    srow[8*ct + 2*g + 1] = pack2(p3[ct][2]*inv3, p3[ct][3]*inv3);
  }
  srow[24 + 2*g + 0] = 0u;   // c = 48..63 zero pad
  srow[24 + 2*g + 1] = 0u;
  asm volatile("s_waitcnt lgkmcnt(0)" ::: "memory");
  const bf16x8 pa0 = *(const bf16x8*)&s_att[r][ 0 + 8*g];
  const bf16x8 pa1 = *(const bf16x8*)&s_att[r][32 + 8*g];

  // ---- PV: out[16 x 512] = attn2[16 x 64] @ vp[64 x 512] ----
  const bf16x8* vpf = (const bf16x8*)vpfrag + (size_t)b * 32 * 2 * 64 + lane;
  float* outb = out + ((size_t)b * Nn + nw) * Ee;
  #pragma unroll 8
  for (int nt = 0; nt < 32; nt++) {
    bf16x8 vf0 = vpf[(nt*2 + 0)*64];
    bf16x8 vf1 = vpf[(nt*2 + 1)*64];
    f32x4 o = {0,0,0,0};
    o = __builtin_amdgcn_mfma_f32_16x16x32_bf16(pa0, vf0, o, 0,0,0);
    o = __builtin_amdgcn_mfma_f32_16x16x32_bf16(pa1, vf1, o, 0,0,0);
    #pragma unroll
    for (int rg = 0; rg < 4; rg++)
      outb[(size_t)(4*g + rg) * Ee + nt*16 + r] = o[rg];
  }
}

extern "C" void kernel_launch(void* const* d_in, const int* in_sizes, int n_in,
                              void* d_out, int out_size, void* d_ws, size_t ws_size,
                              hipStream_t stream) {
  const float* q   = (const float*)d_in[0];
  const float* k   = (const float*)d_in[1];
  const float* v   = (const float*)d_in[2];
  const float* cps = (const float*)d_in[3];
  const float* Wq  = (const float*)d_in[4];
  const float* bq  = (const float*)d_in[5];
  const float* Wk  = (const float*)d_in[6];
  const float* bk  = (const float*)d_in[7];
  const float* Wv  = (const float*)d_in[8];
  const float* bv  = (const float*)d_in[9];
  float* out = (float*)d_out;
  char* ws = (char*)d_ws;

  // ws layout (~1.97 MB total)
  float*          Mt    = (float*)(ws);                        // 2*256*512*4 = 1048576
  float*          tvec  = (float*)(ws + 1048576);              // 512*4  = 2048
  float*          uvec  = (float*)(ws + 1050624);              // 256*4  = 1024
  float*          bqbkp = (float*)(ws + 1051648);              // 4 (pad to 1024)
  unsigned short* abf   = (unsigned short*)(ws + 1052672);     // 393216
  unsigned short* vpf   = (unsigned short*)(ws + 1052672 + 393216);          // 524288
  float*          dbias = (float*)(ws + 1052672 + 393216 + 524288);          // 2048

  prepA_kernel<<<dim3(9, 4, 2), 256, 0, stream>>>(Wq, Wk, bq, bk, Mt, tvec, uvec, bqbkp);
  prepB_kernel<<<dim3(112, 4),  256, 0, stream>>>(k, v, Wv, bv, Mt, tvec, uvec, bqbkp,
                                                  abf, vpf, dbias);
  main_kernel <<<dim3(8192),     64, 0, stream>>>(q, cps, abf, vpf, dbias, out);
}

// Round 5
// 174.609 us; speedup vs baseline: 2.1623x; 1.1806x over previous
//
#include <hip/hip_runtime.h>
#include <hip/hip_bf16.h>
#include <stdint.h>

#define Bb 8
#define Nn 16384
#define Cc 40
#define Ee 512
#define Dd 256

typedef __attribute__((ext_vector_type(4))) float f32x4;
typedef __attribute__((ext_vector_type(8))) short bf16x8;

__device__ __forceinline__ unsigned short f2bf(float f) {
  union { float f; uint32_t u; } x; x.f = f;
  uint32_t r = x.u + 0x7FFFu + ((x.u >> 16) & 1u);   // round-to-nearest-even
  return (unsigned short)(r >> 16);
}
__device__ __forceinline__ unsigned int pack2(float a, float b) {
  return (unsigned int)f2bf(a) | ((unsigned int)f2bf(b) << 16);
}
__device__ __forceinline__ bf16x8 q2bf(float4 a, float4 c) {
  union { __hip_bfloat162 h2[4]; bf16x8 v; } u;
  u.h2[0] = __float22bfloat162_rn(float2{a.x, a.y});
  u.h2[1] = __float22bfloat162_rn(float2{a.z, a.w});
  u.h2[2] = __float22bfloat162_rn(float2{c.x, c.y});
  u.h2[3] = __float22bfloat162_rn(float2{c.z, c.w});
  return u.v;
}

// ---------------- prepA: Mt[z][d][e] = sum_{f half z} Wq[f][e]*Wk[f][d];
//                  plus (bx==8,bz==0): tvec/uvec/bqbk bias vectors ----------------
// grid (9,4,2), 256 thr.
__global__ __launch_bounds__(256) void prepA_kernel(
    const float* __restrict__ Wq, const float* __restrict__ Wk,
    const float* __restrict__ bq, const float* __restrict__ bk,
    float* __restrict__ Mt, float* __restrict__ tvec,
    float* __restrict__ uvec, float* __restrict__ bqbk) {
  const int t = threadIdx.x;
  if (blockIdx.x == 8) {
    if (blockIdx.z != 0) return;
    const int by = blockIdx.y;
    if (by < 2) {
      const int e = by * 256 + t;
      float s = 0.f;
      #pragma unroll 8
      for (int f = 0; f < Ee; f++) s += Wq[(size_t)f * Ee + e] * bk[f];
      tvec[e] = s;
    } else if (by == 2) {
      const int d = t;
      float s = 0.f;
      #pragma unroll 8
      for (int f = 0; f < Ee; f++) s += Wk[(size_t)f * Dd + d] * bq[f];
      uvec[d] = s;
    } else {
      __shared__ float red[256];
      float p = 0.f;
      for (int f = t; f < Ee; f += 256) p += bq[f] * bk[f];
      red[t] = p; __syncthreads();
      #pragma unroll
      for (int off = 128; off > 0; off >>= 1) {
        if (t < off) red[t] += red[t + off];
        __syncthreads();
      }
      if (t == 0) bqbk[0] = red[0];
    }
    return;
  }
  __shared__ float WqL[64][68];
  __shared__ float WkL[64][68];
  const int te = (t & 15) * 4;
  const int td = (t >> 4) * 4;
  const int ebase = blockIdx.x * 64, dbase = blockIdx.y * 64;
  const int fbase = blockIdx.z * 256;
  f32x4 acc0 = {0,0,0,0}, acc1 = {0,0,0,0}, acc2 = {0,0,0,0}, acc3 = {0,0,0,0};
  for (int f0 = 0; f0 < 256; f0 += 64) {
    __syncthreads();
    #pragma unroll
    for (int i = 0; i < 4; i++) {
      int idx = t + i * 256;
      int row = idx >> 4, c4 = (idx & 15) * 4;
      *(float4*)&WqL[row][c4] = *(const float4*)(Wq + (size_t)(fbase + f0 + row) * Ee + ebase + c4);
      *(float4*)&WkL[row][c4] = *(const float4*)(Wk + (size_t)(fbase + f0 + row) * Dd + dbase + c4);
    }
    __syncthreads();
    #pragma unroll 8
    for (int ff = 0; ff < 64; ff++) {
      float4 a = *(const float4*)&WkL[ff][td];
      float4 b = *(const float4*)&WqL[ff][te];
      acc0[0] += a.x*b.x; acc0[1] += a.x*b.y; acc0[2] += a.x*b.z; acc0[3] += a.x*b.w;
      acc1[0] += a.y*b.x; acc1[1] += a.y*b.y; acc1[2] += a.y*b.z; acc1[3] += a.y*b.w;
      acc2[0] += a.z*b.x; acc2[1] += a.z*b.y; acc2[2] += a.z*b.z; acc2[3] += a.z*b.w;
      acc3[0] += a.w*b.x; acc3[1] += a.w*b.y; acc3[2] += a.w*b.z; acc3[3] += a.w*b.w;
    }
  }
  float* mt = Mt + (size_t)blockIdx.z * 131072;
  *(f32x4*)&mt[(size_t)(dbase + td + 0) * Ee + ebase + te] = acc0;
  *(f32x4*)&mt[(size_t)(dbase + td + 1) * Ee + ebase + te] = acc1;
  *(f32x4*)&mt[(size_t)(dbase + td + 2) * Ee + ebase + te] = acc2;
  *(f32x4*)&mt[(size_t)(dbase + td + 3) * Ee + ebase + te] = acc3;
}

// ---------------- prepB: bx<48 -> A-frags(G)+dbias; bx>=48 -> B-frags(vp) --------
// grid (112,4), 256 thr.
__global__ __launch_bounds__(256) void prepB_kernel(
    const float* __restrict__ k, const float* __restrict__ v,
    const float* __restrict__ Wv, const float* __restrict__ bv,
    const float* __restrict__ Mt, const float* __restrict__ tvec,
    const float* __restrict__ uvec, const float* __restrict__ bqbk,
    unsigned short* __restrict__ abf, unsigned short* __restrict__ vpf,
    float* __restrict__ dbias) {
  __shared__ float xL[8][Dd];
  const int t = threadIdx.x;
  const int el = t & 127, half = t >> 7;
  const int e = blockIdx.y * 128 + el;

  if (blockIdx.x < 48) {
    const int sbase = blockIdx.x * 8;
    for (int i = t; i < 8 * Dd; i += 256) {
      int row = i >> 8, dd = i & (Dd - 1);
      int sg = sbase + row, bb_ = sg / 48, cc = sg % 48;
      xL[row][dd] = (cc < 40) ? k[((size_t)bb_ * Cc + cc) * Dd + dd] : 0.f;
    }
    __syncthreads();
    float acc[4] = {0,0,0,0};
    float db[4]  = {0,0,0,0};
    #pragma unroll 8
    for (int d = 0; d < Dd; d++) {
      float mt = Mt[(size_t)d * Ee + e] + Mt[131072 + (size_t)d * Ee + e];
      float ud = uvec[d];
      #pragma unroll
      for (int si = 0; si < 4; si++) {
        float kv = xL[half*4 + si][d];
        acc[si] += mt * kv;
        db[si]  += ud * kv;
      }
    }
    const float scale = 0.044194173824159216f;  // 1/sqrt(512)
    const float te = tvec[e];
    const float bqbkv = bqbk[0];
    const int ks = e >> 5, gg = (e >> 3) & 3, j = e & 7;
    #pragma unroll
    for (int si = 0; si < 4; si++) {
      int sg = sbase + half*4 + si, bb_ = sg / 48, cc = sg % 48;
      int ct = cc >> 4, lane16 = (cc & 15) + 16*gg;
      unsigned short val = (cc < 40) ? f2bf(scale * (acc[si] + te)) : (unsigned short)0;
      abf[((((size_t)bb_*3 + ct)*16 + ks)*64 + lane16)*8 + j] = val;
      if (el == 0) dbias[bb_*64 + cc] = (cc < 40) ? scale * (db[si] + bqbkv) : 0.f;
    }
  } else {
    const int sbase = (blockIdx.x - 48) * 8;
    for (int i = t; i < 8 * Dd; i += 256) {
      int row = i >> 8, dd = i & (Dd - 1);
      int sg = sbase + row, bb_ = sg >> 6, cc = sg & 63;
      xL[row][dd] = (cc < 40) ? v[((size_t)bb_ * Cc + cc) * Dd + dd] : 0.f;
    }
    __syncthreads();
    const float* wrow = Wv + (size_t)e * Dd;
    float acc[4] = {0,0,0,0};
    #pragma unroll 2
    for (int dd = 0; dd < Dd; dd += 4) {
      float4 w = *(const float4*)(wrow + dd);
      #pragma unroll
      for (int si = 0; si < 4; si++) {
        float4 vv = *(const float4*)&xL[half*4 + si][dd];
        acc[si] += w.x*vv.x + w.y*vv.y + w.z*vv.z + w.w*vv.w;
      }
    }
    const float bve = bv[e];
    const int nt = e >> 4, elan = e & 15;
    #pragma unroll
    for (int si = 0; si < 4; si++) {
      int sg = sbase + half*4 + si, bb_ = sg >> 6, cc = sg & 63;
      int s = cc >> 5, gg = (cc >> 3) & 3, j = cc & 7;
      unsigned short val = (cc < 40) ? f2bf(acc[si] + bve) : (unsigned short)0;
      vpf[((((size_t)bb_*32 + nt)*2 + s)*64 + (elan + 16*gg))*8 + j] = val;
    }
  }
}

// ---------------- main: frags staged in LDS; 8 waves/block; transposed PV --------
// grid 256 (1 block/CU): block = (batch b = bx>>5, segment seg = bx&31).
// Block stages abf(48KB)+vpf(64KB) in LDS once, then 4 iterations x 8 waves x 16 rows.
__global__ __launch_bounds__(512, 2) void main_kernel(
    const float* __restrict__ q, const float* __restrict__ coarse,
    const unsigned short* __restrict__ abfrag,
    const unsigned short* __restrict__ vpfrag,
    const float* __restrict__ dbias, float* __restrict__ out) {
  __shared__ uint4 fragL[7168];                 // 112 KB: [0,3072)=abf, [3072,7168)=vpf
  __shared__ unsigned short s_att[8][16][72];   // 18 KB per-wave attn re-fragment
  const int t = threadIdx.x;
  const int wave = t >> 6, lane = t & 63;
  const int r = lane & 15, g = lane >> 4;
  const int b = blockIdx.x >> 5;
  const int seg = blockIdx.x & 31;
  const bool v2 = (g < 2);

  // dbias (per batch, hoisted; latency hides under staging)
  const float4 db0 = *(const float4*)(dbias + b*64 +  0 + 4*g);
  const float4 db1 = *(const float4*)(dbias + b*64 + 16 + 4*g);
  const float4 db2 = *(const float4*)(dbias + b*64 + 32 + 4*g);

  // ---- stage fragments to LDS (once per block) ----
  {
    const uint4* srcA = (const uint4*)abfrag + (size_t)b * 3072;
    #pragma unroll
    for (int i = 0; i < 6; i++) fragL[t + i*512] = srcA[t + i*512];
    const uint4* srcV = (const uint4*)vpfrag + (size_t)b * 4096;
    #pragma unroll
    for (int i = 0; i < 8; i++) fragL[3072 + t + i*512] = srcV[t + i*512];
  }
  __syncthreads();

  const int row0 = seg * 512 + wave * 16;                 // this wave's first row (it=0)
  const float* qrow0 = q + ((size_t)b * Nn + row0 + r) * Ee + 8 * g;
  const float* cbase0 = coarse + (size_t)b * Cc * Nn + row0 + r;
  float* outb0 = out + ((size_t)b * Nn + row0 + r) * Ee + 4 * g;

  f32x4 acc0, acc1, acc2;
  float4 H0[16], H1[16];

  auto LOADH = [&](const float* qr, int h, float4* H) {
    #pragma unroll
    for (int j = 0; j < 8; j++) {
      H[2*j]   = *(const float4*)(qr + 256*h + 32*j);
      H[2*j+1] = *(const float4*)(qr + 256*h + 32*j + 4);
    }
  };
  auto COMP = [&](const float4* H, int h) {
    #pragma unroll
    for (int j = 0; j < 8; j++) {
      bf16x8 qf = q2bf(H[2*j], H[2*j+1]);
      const int ks = 8*h + j;
      acc0 = __builtin_amdgcn_mfma_f32_16x16x32_bf16(*(const bf16x8*)&fragL[(0*16+ks)*64 + lane], qf, acc0, 0,0,0);
      acc1 = __builtin_amdgcn_mfma_f32_16x16x32_bf16(*(const bf16x8*)&fragL[(1*16+ks)*64 + lane], qf, acc1, 0,0,0);
      acc2 = __builtin_amdgcn_mfma_f32_16x16x32_bf16(*(const bf16x8*)&fragL[(2*16+ks)*64 + lane], qf, acc2, 0,0,0);
    }
  };

  LOADH(qrow0, 0, H0);   // prologue: tile 0, first half

  for (int it = 0; it < 4; it++) {
    const float* qr = qrow0 + (size_t)(it*128) * Ee;
    LOADH(qr, 1, H1);
    acc0 = f32x4{0,0,0,0}; acc1 = f32x4{0,0,0,0}; acc2 = f32x4{0,0,0,0};
    COMP(H0, 0);

    // coarse_pred loads (independent; latency hides under COMP)
    const float* cb = cbase0 + it*128;
    float cr[3][4];
    #pragma unroll
    for (int rg = 0; rg < 4; rg++) {
      cr[0][rg] = cb[(size_t)( 0 + 4*g + rg) * Nn];
      cr[1][rg] = cb[(size_t)(16 + 4*g + rg) * Nn];
      cr[2][rg] = v2 ? cb[(size_t)(32 + 4*g + rg) * Nn] : -3e38f;
    }

    COMP(H1, 1);

    float L[3][4];
    #pragma unroll
    for (int rg = 0; rg < 4; rg++) {
      L[0][rg] = acc0[rg] + ((const float*)&db0)[rg];
      L[1][rg] = acc1[rg] + ((const float*)&db1)[rg];
      L[2][rg] = acc2[rg] + ((const float*)&db2)[rg];
    }

    // ---- softmax #1 over c ----
    float m1 = -3e38f;
    #pragma unroll
    for (int rg = 0; rg < 4; rg++) {
      m1 = fmaxf(m1, L[0][rg]); m1 = fmaxf(m1, L[1][rg]);
      if (v2) m1 = fmaxf(m1, L[2][rg]);
    }
    m1 = fmaxf(m1, __shfl_xor(m1, 16));
    m1 = fmaxf(m1, __shfl_xor(m1, 32));
    float p[3][4]; float s1 = 0.f;
    #pragma unroll
    for (int rg = 0; rg < 4; rg++) {
      p[0][rg] = __expf(L[0][rg] - m1); s1 += p[0][rg];
      p[1][rg] = __expf(L[1][rg] - m1); s1 += p[1][rg];
      p[2][rg] = v2 ? __expf(L[2][rg] - m1) : 0.f; s1 += p[2][rg];
    }
    s1 += __shfl_xor(s1, 16); s1 += __shfl_xor(s1, 32);
    const float inv1 = 1.0f / s1;

    // ---- cp = softmax_c(coarse_pred) ----
    float m2 = -3e38f;
    #pragma unroll
    for (int rg = 0; rg < 4; rg++) {
      m2 = fmaxf(m2, cr[0][rg]); m2 = fmaxf(m2, cr[1][rg]);
      if (v2) m2 = fmaxf(m2, cr[2][rg]);
    }
    m2 = fmaxf(m2, __shfl_xor(m2, 16));
    m2 = fmaxf(m2, __shfl_xor(m2, 32));
    float cpv[3][4]; float s2 = 0.f;
    #pragma unroll
    for (int rg = 0; rg < 4; rg++) {
      cpv[0][rg] = __expf(cr[0][rg] - m2); s2 += cpv[0][rg];
      cpv[1][rg] = __expf(cr[1][rg] - m2); s2 += cpv[1][rg];
      cpv[2][rg] = v2 ? __expf(cr[2][rg] - m2) : 0.f; s2 += cpv[2][rg];
    }
    s2 += __shfl_xor(s2, 16); s2 += __shfl_xor(s2, 32);
    const float inv2 = 1.0f / s2;

    // ---- softmax #2 over c of (attn1 * cp) ----
    const float sc12 = inv1 * inv2;
    float w[3][4];
    float m3 = -3e38f;
    #pragma unroll
    for (int rg = 0; rg < 4; rg++) {
      w[0][rg] = p[0][rg] * cpv[0][rg] * sc12;
      w[1][rg] = p[1][rg] * cpv[1][rg] * sc12;
      w[2][rg] = v2 ? (p[2][rg] * cpv[2][rg] * sc12) : 0.f;
      m3 = fmaxf(m3, w[0][rg]); m3 = fmaxf(m3, w[1][rg]);
      if (v2) m3 = fmaxf(m3, w[2][rg]);
    }
    m3 = fmaxf(m3, __shfl_xor(m3, 16));
    m3 = fmaxf(m3, __shfl_xor(m3, 32));
    float p3[3][4]; float s3 = 0.f;
    #pragma unroll
    for (int rg = 0; rg < 4; rg++) {
      p3[0][rg] = __expf(w[0][rg] - m3); s3 += p3[0][rg];
      p3[1][rg] = __expf(w[1][rg] - m3); s3 += p3[1][rg];
      p3[2][rg] = v2 ? __expf(w[2][rg] - m3) : 0.f; s3 += p3[2][rg];
    }
    s3 += __shfl_xor(s3, 16); s3 += __shfl_xor(s3, 32);
    const float inv3 = 1.0f / s3;

    // ---- prefetch next tile's first q-half before the PV phase ----
    if (it < 3) LOADH(qrow0 + (size_t)((it+1)*128) * Ee, 0, H0);

    // ---- re-fragment attn2 via per-wave LDS round-trip ----
    unsigned int* srow = (unsigned int*)&s_att[wave][r][0];
    #pragma unroll
    for (int ct = 0; ct < 3; ct++) {
      srow[8*ct + 2*g + 0] = pack2(p3[ct][0]*inv3, p3[ct][1]*inv3);
      srow[8*ct + 2*g + 1] = pack2(p3[ct][2]*inv3, p3[ct][3]*inv3);
    }
    srow[24 + 2*g + 0] = 0u;   // c = 48..63 zero pad
    srow[24 + 2*g + 1] = 0u;
    asm volatile("s_waitcnt lgkmcnt(0)" ::: "memory");
    const bf16x8 pa0 = *(const bf16x8*)&s_att[wave][r][ 0 + 8*g];
    const bf16x8 pa1 = *(const bf16x8*)&s_att[wave][r][32 + 8*g];

    // ---- PV transposed: outT = vp^T @ attn^T; lane stores float4 of row r ----
    float* outp = outb0 + (size_t)(it*128) * Ee;
    #pragma unroll 8
    for (int nt = 0; nt < 32; nt++) {
      bf16x8 vf0 = *(const bf16x8*)&fragL[3072 + (nt*2 + 0)*64 + lane];
      bf16x8 vf1 = *(const bf16x8*)&fragL[3072 + (nt*2 + 1)*64 + lane];
      f32x4 o = {0,0,0,0};
      o = __builtin_amdgcn_mfma_f32_16x16x32_bf16(vf0, pa0, o, 0,0,0);
      o = __builtin_amdgcn_mfma_f32_16x16x32_bf16(vf1, pa1, o, 0,0,0);
      *(f32x4*)(outp + nt*16) = o;   // out[row r][nt*16 + 4g .. +3]
    }
  }
}

extern "C" void kernel_launch(void* const* d_in, const int* in_sizes, int n_in,
                              void* d_out, int out_size, void* d_ws, size_t ws_size,
                              hipStream_t stream) {
  const float* q   = (const float*)d_in[0];
  const float* k   = (const float*)d_in[1];
  const float* v   = (const float*)d_in[2];
  const float* cps = (const float*)d_in[3];
  const float* Wq  = (const float*)d_in[4];
  const float* bq  = (const float*)d_in[5];
  const float* Wk  = (const float*)d_in[6];
  const float* bk  = (const float*)d_in[7];
  const float* Wv  = (const float*)d_in[8];
  const float* bv  = (const float*)d_in[9];
  float* out = (float*)d_out;
  char* ws = (char*)d_ws;

  // ws layout (~1.97 MB total)
  float*          Mt    = (float*)(ws);                        // 2*256*512*4 = 1048576
  float*          tvec  = (float*)(ws + 1048576);              // 512*4  = 2048
  float*          uvec  = (float*)(ws + 1050624);              // 256*4  = 1024
  float*          bqbkp = (float*)(ws + 1051648);              // 4 (pad to 1024)
  unsigned short* abf   = (unsigned short*)(ws + 1052672);     // 393216
  unsigned short* vpf   = (unsigned short*)(ws + 1052672 + 393216);          // 524288
  float*          dbias = (float*)(ws + 1052672 + 393216 + 524288);          // 2048

  prepA_kernel<<<dim3(9, 4, 2), 256, 0, stream>>>(Wq, Wk, bq, bk, Mt, tvec, uvec, bqbkp);
  prepB_kernel<<<dim3(112, 4),  256, 0, stream>>>(k, v, Wv, bv, Mt, tvec, uvec, bqbkp,
                                                  abf, vpf, dbias);
  main_kernel <<<dim3(256),     512, 0, stream>>>(q, cps, abf, vpf, dbias, out);
}